// Round 2
// baseline (481.079 us; speedup 1.0000x reference)
//
#include <hip/hip_runtime.h>
#include <hip/hip_bf16.h>

// Problem constants
#define DIM   512
#define NTR   16384
#define NT    8192
#define NCLS  16
#define NROWS (NTR + NT)   // 24576 projection rows

// Main-kernel tiling
#define JCHUNK 512                 // train points staged per block
#define NJ     (NTR / JCHUNK)      // 32 j-chunks
#define IBLK   512                 // test points per block
#define NIB    (NT / IBLK)         // 16 i-blocks  -> grid 16x32 = 512 blocks
#define GSIZE  128                 // threads per j-group (2 groups of 128)
#define IPT    4                   // test points per thread

// ws layout (floats):
//   [0, 49152)        kq: [24576][2]; rows [0,NTR)=k (train), [NTR,NROWS)=q (test)
//   [49152, 180224)   numer [8192][16]
//   [180224, 188416)  denom [8192]
#define WS_KQ_F    (NROWS * 2)           // 49152
#define WS_NUMER_F (NT * NCLS)           // 131072
#define WS_DENOM_F (NT)                  // 8192

// ---------------------------------------------------------------------------
// Kernel 1: fused projection. One wave per row (512-dim dot with A's 2 cols).
// Rows [0,NTR) come from xtr, rows [NTR,NROWS) from xt. Memory-bound: 48 MB.
// ---------------------------------------------------------------------------
__global__ __launch_bounds__(256) void proj_kernel(
    const float* __restrict__ xtr, const float* __restrict__ xt,
    const float* __restrict__ A, float* __restrict__ kq)
{
    const int wave = threadIdx.x >> 6;
    const int lane = threadIdx.x & 63;
    const int row  = blockIdx.x * 4 + wave;

    const float* x = (row < NTR) ? (xtr + (size_t)row * DIM)
                                 : (xt + (size_t)(row - NTR) * DIM);
    float a0 = 0.f, a1 = 0.f;
#pragma unroll
    for (int t = 0; t < 2; ++t) {
        const int d = lane * 4 + t * 256;          // coalesced float4 across lanes
        float4 xv = *(const float4*)(x + d);
        float4 A0 = *(const float4*)(A + 2 * d);       // A[d..d+1][0..1]
        float4 A1 = *(const float4*)(A + 2 * d + 4);   // A[d+2..d+3][0..1]
        a0 += xv.x * A0.x + xv.y * A0.z + xv.z * A1.x + xv.w * A1.z;
        a1 += xv.x * A0.y + xv.y * A0.w + xv.z * A1.y + xv.w * A1.w;
    }
#pragma unroll
    for (int off = 32; off >= 1; off >>= 1) {
        a0 += __shfl_xor(a0, off, 64);
        a1 += __shfl_xor(a1, off, 64);
    }
    if (lane == 0) {
        kq[row * 2 + 0] = a0;
        kq[row * 2 + 1] = a1;
    }
}

// ---------------------------------------------------------------------------
// Kernel 2: main. Grid (NIB, NJ) = (16, 32) = 512 blocks, 2/CU.
// Block covers 512 i's x 512 j's. Each thread owns IPT=4 i's (so one set of
// y-loads per jj feeds 4 pairs -> 4x less LDS data-return than round 1).
// The 512-j chunk is split across 2 thread-groups of 128 (waves 0-1 / 2-3);
// their partials are combined through LDS so the global atomic count stays
// at round-1's 4.45M (WRITE_SIZE showed atomics write through to HBM at
// ~32 B/atomic -- don't grow them).
// ---------------------------------------------------------------------------
__global__ __launch_bounds__(256) void simmain_kernel(
    const float* __restrict__ kq, const float* __restrict__ ytr,
    float* __restrict__ numer, float* __restrict__ denom)
{
    // smem: [0, 8192) = ys staging (512x16), [8192, 9216) = ks (512 float2)
    // After the j-loop, the front of smem is reused as the 128x4x17 combine
    // scratch (8704 floats <= 9216).
    __shared__ float smem[JCHUNK * NCLS + JCHUNK * 2];   // 36 KB
    float2* ks = (float2*)(smem + JCHUNK * NCLS);
    float*  ys = smem;

    const int tid = threadIdx.x;
    const int i0  = blockIdx.x * IBLK;
    const int j0  = blockIdx.y * JCHUNK;

    // Stage k chunk (512 float2) and ytr chunk (512x16 = 32 KB)
    for (int r = tid; r < JCHUNK; r += 256)
        ks[r] = *(const float2*)(kq + 2 * (j0 + r));
    {
        const float4* ysrc = (const float4*)(ytr + (size_t)j0 * NCLS);
        float4* ydst = (float4*)ys;
#pragma unroll
        for (int p = 0; p < (JCHUNK * NCLS / 4) / 256; ++p)
            ydst[tid + 256 * p] = ysrc[tid + 256 * p];
    }
    __syncthreads();

    const int g     = tid & (GSIZE - 1);         // 0..127: which i-set
    const int jbase = (tid >> 7) * (JCHUNK / 2); // 0 or 256: which j-half

    float q0[IPT], q1[IPT];
#pragma unroll
    for (int ii = 0; ii < IPT; ++ii) {
        float2 qv = *(const float2*)(kq + 2 * (NTR + i0 + g + GSIZE * ii));
        q0[ii] = qv.x; q1[ii] = qv.y;
    }

    float acc[IPT][NCLS + 1];                    // [ii][16] = denominator
#pragma unroll
    for (int ii = 0; ii < IPT; ++ii)
#pragma unroll
        for (int c = 0; c <= NCLS; ++c) acc[ii][c] = 0.f;

#pragma unroll 2
    for (int jj = jbase; jj < jbase + JCHUNK / 2; ++jj) {
        const float2 kv = ks[jj];
        const float4* y = (const float4*)(ys + jj * NCLS);
        const float4 y0 = y[0], y1 = y[1], y2 = y[2], y3 = y[3];
        float e[IPT];
#pragma unroll
        for (int ii = 0; ii < IPT; ++ii) {
            e[ii] = __expf(fmaf(q1[ii], kv.y, q0[ii] * kv.x));
            acc[ii][16] += e[ii];
        }
#pragma unroll
        for (int ii = 0; ii < IPT; ++ii) {
            acc[ii][0]  += e[ii] * y0.x; acc[ii][1]  += e[ii] * y0.y;
            acc[ii][2]  += e[ii] * y0.z; acc[ii][3]  += e[ii] * y0.w;
            acc[ii][4]  += e[ii] * y1.x; acc[ii][5]  += e[ii] * y1.y;
            acc[ii][6]  += e[ii] * y1.z; acc[ii][7]  += e[ii] * y1.w;
            acc[ii][8]  += e[ii] * y2.x; acc[ii][9]  += e[ii] * y2.y;
            acc[ii][10] += e[ii] * y2.z; acc[ii][11] += e[ii] * y2.w;
            acc[ii][12] += e[ii] * y3.x; acc[ii][13] += e[ii] * y3.y;
            acc[ii][14] += e[ii] * y3.z; acc[ii][15] += e[ii] * y3.w;
        }
    }

    __syncthreads();   // ys/ks dead; reuse smem as combine scratch

    float* scratch = smem;   // [ii*GSIZE + g][17]
    if (tid >= GSIZE) {      // j-group 1 parks its partials in LDS
#pragma unroll
        for (int ii = 0; ii < IPT; ++ii)
#pragma unroll
            for (int c = 0; c <= NCLS; ++c)
                scratch[(ii * GSIZE + g) * 17 + c] = acc[ii][c];
    }
    __syncthreads();
    if (tid < GSIZE) {       // j-group 0 combines and flushes
#pragma unroll
        for (int ii = 0; ii < IPT; ++ii) {
            const int i = i0 + g + GSIZE * ii;
            const float* sc = scratch + (ii * GSIZE + g) * 17;
#pragma unroll
            for (int c = 0; c < NCLS; ++c)
                atomicAdd(&numer[(size_t)i * NCLS + c], acc[ii][c] + sc[c]);
            atomicAdd(&denom[i], acc[ii][16] + sc[16]);
        }
    }
}

// ---------------------------------------------------------------------------
// Kernel 3: finalize — divide numerators by softmax denominator.
// ---------------------------------------------------------------------------
__global__ __launch_bounds__(256) void finalize_kernel(
    const float* __restrict__ numer, const float* __restrict__ denom,
    float* __restrict__ out)
{
    const int idx = blockIdx.x * 256 + threadIdx.x;   // < NT*NCLS
    out[idx] = numer[idx] / denom[idx >> 4];
}

// ---------------------------------------------------------------------------
extern "C" void kernel_launch(void* const* d_in, const int* in_sizes, int n_in,
                              void* d_out, int out_size, void* d_ws, size_t ws_size,
                              hipStream_t stream)
{
    const float* xtr = (const float*)d_in[0];   // [16384][512]
    const float* ytr = (const float*)d_in[1];   // [16384][16]
    const float* xt  = (const float*)d_in[2];   // [8192][512]
    const float* A   = (const float*)d_in[3];   // [512][2]
    float* out = (float*)d_out;                 // [8192][16]

    float* kq    = (float*)d_ws;                // 49152 floats
    float* numer = kq + WS_KQ_F;                // 131072 floats
    float* denom = numer + WS_NUMER_F;          // 8192 floats

    // ws is poisoned 0xAA before every call: zero the accumulators.
    hipMemsetAsync(numer, 0, (WS_NUMER_F + WS_DENOM_F) * sizeof(float), stream);

    proj_kernel<<<NROWS / 4, 256, 0, stream>>>(xtr, xt, A, kq);
    simmain_kernel<<<dim3(NIB, NJ), 256, 0, stream>>>(kq, ytr, numer, denom);
    finalize_kernel<<<(NT * NCLS) / 256, 256, 0, stream>>>(numer, denom, out);
}

// Round 3
// 388.332 us; speedup vs baseline: 1.2388x; 1.2388x over previous
//
#include <hip/hip_runtime.h>
#include <hip/hip_bf16.h>

// Problem constants
#define DIM   512
#define NTR   16384
#define NT    8192
#define NCLS  16
#define NROWS (NTR + NT)   // 24576 projection rows

// Main-kernel tiling: grid (NT/256, JSPLIT). Each wave owns 64 i's (one per
// lane) and one 512-long j-chunk. j is wave-uniform -> k[j] and ytr[j][:]
// are scalar-loaded into SGPRs; the inner loop has NO LDS and NO vector
// memory ops.
#define JSPLIT 32
#define JC     (NTR / JSPLIT)      // 512 j's per chunk

// ws layout (floats):
//   [0, 49152)        kq: [24576][2]; rows [0,NTR)=k (train), [NTR,NROWS)=q (test)
//   [49152, 180224)   numer [8192][16]
//   [180224, 188416)  denom [8192]
#define WS_KQ_F    (NROWS * 2)           // 49152
#define WS_NUMER_F (NT * NCLS)           // 131072
#define WS_DENOM_F (NT)                  // 8192

// ---------------------------------------------------------------------------
// Kernel 1: fused projection. One wave per row (512-dim dot with A's 2 cols).
// Rows [0,NTR) come from xtr, rows [NTR,NROWS) from xt. Memory-bound: 48 MB.
// ---------------------------------------------------------------------------
__global__ __launch_bounds__(256) void proj_kernel(
    const float* __restrict__ xtr, const float* __restrict__ xt,
    const float* __restrict__ A, float* __restrict__ kq)
{
    const int wave = threadIdx.x >> 6;
    const int lane = threadIdx.x & 63;
    const int row  = blockIdx.x * 4 + wave;

    const float* x = (row < NTR) ? (xtr + (size_t)row * DIM)
                                 : (xt + (size_t)(row - NTR) * DIM);
    float a0 = 0.f, a1 = 0.f;
#pragma unroll
    for (int t = 0; t < 2; ++t) {
        const int d = lane * 4 + t * 256;          // coalesced float4 across lanes
        float4 xv = *(const float4*)(x + d);
        float4 A0 = *(const float4*)(A + 2 * d);       // A[d..d+1][0..1]
        float4 A1 = *(const float4*)(A + 2 * d + 4);   // A[d+2..d+3][0..1]
        a0 += xv.x * A0.x + xv.y * A0.z + xv.z * A1.x + xv.w * A1.z;
        a1 += xv.x * A0.y + xv.y * A0.w + xv.z * A1.y + xv.w * A1.w;
    }
#pragma unroll
    for (int off = 32; off >= 1; off >>= 1) {
        a0 += __shfl_xor(a0, off, 64);
        a1 += __shfl_xor(a1, off, 64);
    }
    if (lane == 0) {
        kq[row * 2 + 0] = a0;
        kq[row * 2 + 1] = a1;
    }
}

// ---------------------------------------------------------------------------
// Kernel 2: main. Grid (NT/256, JSPLIT) = (32, 32) = 1024 blocks (16 waves/CU,
// round-1's proven occupancy). Lane owns test point i = blockIdx.x*256 + tid;
// all 4 waves of a block walk the SAME wave-uniform j-chunk, so per-j k and
// ytr values compile to s_load (SGPR broadcast, scalar cache) and the label
// aggregation is 16 x v_fmac_f32 with an SGPR multiplicand. Inner loop:
// ~21 VALU ops, 0 LDS ops, 0 VMEM ops per 64 pairs.
// Partials flushed with atomicAdd (32 writers/address, as in round 1).
// ---------------------------------------------------------------------------
__global__ __launch_bounds__(256) void simmain_kernel(
    const float* __restrict__ kq, const float* __restrict__ ytr,
    float* __restrict__ numer, float* __restrict__ denom)
{
    const int i  = blockIdx.x * 256 + threadIdx.x;
    const int j0 = blockIdx.y * JC;

    const float2 qv = *(const float2*)(kq + 2 * (NTR + i));
    const float q0 = qv.x, q1 = qv.y;

    float acc[NCLS];
#pragma unroll
    for (int c = 0; c < NCLS; ++c) acc[c] = 0.f;
    float dsum = 0.f;

    const float* __restrict__ kp = kq + 2 * j0;      // wave-uniform base
    const float* __restrict__ yp = ytr + (size_t)j0 * NCLS;

#pragma unroll 2
    for (int jj = 0; jj < JC; ++jj) {
        // All operands below are wave-uniform -> scalar loads into SGPRs.
        const float k0 = kp[2 * jj + 0];
        const float k1 = kp[2 * jj + 1];
        const float e  = __expf(fmaf(q1, k1, q0 * k0));   // per-lane
        dsum += e;
        const float* y = yp + jj * NCLS;
#pragma unroll
        for (int c = 0; c < NCLS; ++c)
            acc[c] = fmaf(e, y[c], acc[c]);               // v_fmac v, s, v
    }

    float* nrow = numer + (size_t)i * NCLS;
#pragma unroll
    for (int c = 0; c < NCLS; ++c)
        atomicAdd(nrow + c, acc[c]);
    atomicAdd(denom + i, dsum);
}

// ---------------------------------------------------------------------------
// Kernel 3: finalize — divide numerators by softmax denominator.
// ---------------------------------------------------------------------------
__global__ __launch_bounds__(256) void finalize_kernel(
    const float* __restrict__ numer, const float* __restrict__ denom,
    float* __restrict__ out)
{
    const int idx = blockIdx.x * 256 + threadIdx.x;   // < NT*NCLS
    out[idx] = numer[idx] / denom[idx >> 4];
}

// ---------------------------------------------------------------------------
extern "C" void kernel_launch(void* const* d_in, const int* in_sizes, int n_in,
                              void* d_out, int out_size, void* d_ws, size_t ws_size,
                              hipStream_t stream)
{
    const float* xtr = (const float*)d_in[0];   // [16384][512]
    const float* ytr = (const float*)d_in[1];   // [16384][16]
    const float* xt  = (const float*)d_in[2];   // [8192][512]
    const float* A   = (const float*)d_in[3];   // [512][2]
    float* out = (float*)d_out;                 // [8192][16]

    float* kq    = (float*)d_ws;                // 49152 floats
    float* numer = kq + WS_KQ_F;                // 131072 floats
    float* denom = numer + WS_NUMER_F;          // 8192 floats

    // ws is poisoned 0xAA before every call: zero the accumulators.
    hipMemsetAsync(numer, 0, (WS_NUMER_F + WS_DENOM_F) * sizeof(float), stream);

    proj_kernel<<<NROWS / 4, 256, 0, stream>>>(xtr, xt, A, kq);
    simmain_kernel<<<dim3(NT / 256, JSPLIT), 256, 0, stream>>>(kq, ytr, numer, denom);
    finalize_kernel<<<(NT * NCLS) / 256, 256, 0, stream>>>(numer, denom, out);
}

// Round 4
// 143.660 us; speedup vs baseline: 3.3487x; 2.7031x over previous
//
#include <hip/hip_runtime.h>
#include <hip/hip_bf16.h>
#include <math.h>

// Problem constants
#define DIM   512
#define NTR   16384
#define NT    8192
#define NCLS  16
#define NROWS (NTR + NT)   // 24576 projection rows

// simmain tiling: wave owns a 16-i tile; block = 4 waves = 64 i's, one j-chunk.
#define JS     8                   // j-splits
#define JC     (NTR / JS)          // 2048 j per chunk
#define STEPS  (JC / 32)           // 64 K-steps (32 j each) per wave
#define NSTEPS (NTR / 32)          // 512 global K-steps

// ws layout (bytes):
//   [0,       196608)   kq [24576][2] f32
//   [196608,  720896)   numer [8192][16] f32
//   [720896,  753664)   denom [8192] f32
//   [753664,  1277952)  yfh: 512 steps x 64 lanes x 8 bf16 (A-frag order, hi)
//   [1277952, 1802240)  yfl: same, lo residual
#define WS_KQ_F    (NROWS * 2)           // 49152 floats
#define WS_NUMER_F (NT * NCLS)           // 131072 floats
#define WS_DENOM_F (NT)                  // 8192 floats

typedef __attribute__((ext_vector_type(8))) short short8;
typedef __attribute__((ext_vector_type(4))) float f32x4;

static __device__ __forceinline__ short f2bf(float f) {   // RNE, finite positive-safe
    unsigned u = __float_as_uint(f);
    return (short)((u + 0x7FFFu + ((u >> 16) & 1u)) >> 16);
}
static __device__ __forceinline__ float bf2f(short h) {
    return __uint_as_float(((unsigned)(unsigned short)h) << 16);
}

// ---------------------------------------------------------------------------
// Kernel 1: fused projection. One wave per row (512-dim dot with A's 2 cols).
// ---------------------------------------------------------------------------
__global__ __launch_bounds__(256) void proj_kernel(
    const float* __restrict__ xtr, const float* __restrict__ xt,
    const float* __restrict__ A, float* __restrict__ kq)
{
    const int wave = threadIdx.x >> 6;
    const int lane = threadIdx.x & 63;
    const int row  = blockIdx.x * 4 + wave;

    const float* x = (row < NTR) ? (xtr + (size_t)row * DIM)
                                 : (xt + (size_t)(row - NTR) * DIM);
    float a0 = 0.f, a1 = 0.f;
#pragma unroll
    for (int t = 0; t < 2; ++t) {
        const int d = lane * 4 + t * 256;
        float4 xv = *(const float4*)(x + d);
        float4 A0 = *(const float4*)(A + 2 * d);
        float4 A1 = *(const float4*)(A + 2 * d + 4);
        a0 += xv.x * A0.x + xv.y * A0.z + xv.z * A1.x + xv.w * A1.z;
        a1 += xv.x * A0.y + xv.y * A0.w + xv.z * A1.y + xv.w * A1.w;
    }
#pragma unroll
    for (int off = 32; off >= 1; off >>= 1) {
        a0 += __shfl_xor(a0, off, 64);
        a1 += __shfl_xor(a1, off, 64);
    }
    if (lane == 0) {
        kq[row * 2 + 0] = a0;
        kq[row * 2 + 1] = a1;
    }
}

// ---------------------------------------------------------------------------
// Kernel 1b: bake ytr^T into bf16 hi/lo planes in EXACT MFMA A-fragment order.
// Frag f = s*64 + lane; lane (cls=lane&15, quad=lane>>4) holds
// ytr[s*32 + quad*8 + t][cls], t=0..7. One thread per fragment.
// ---------------------------------------------------------------------------
__global__ __launch_bounds__(256) void prepy_kernel(
    const float* __restrict__ ytr, short* __restrict__ yfh, short* __restrict__ yfl)
{
    const int idx  = blockIdx.x * 256 + threadIdx.x;  // 0 .. NSTEPS*64-1
    const int l    = idx & 63;
    const int s    = idx >> 6;
    const int cls  = l & 15;
    const int jb   = s * 32 + (l >> 4) * 8;
    short8 hi, lo;
#pragma unroll
    for (int t = 0; t < 8; ++t) {
        float v = ytr[(size_t)(jb + t) * NCLS + cls];
        short h = f2bf(v);
        hi[t] = h;
        lo[t] = f2bf(v - bf2f(h));
    }
    ((short8*)yfh)[idx] = hi;
    ((short8*)yfl)[idx] = lo;
}

// ---------------------------------------------------------------------------
// Kernel 2: main. Grid (NT/64, JS) = (128, 8) = 1024 blocks, 4 waves each.
// Wave w owns i-tile (blockIdx.x*4 + w); block stages its 2048-j k-chunk
// (fp32, 16 KB) in LDS once; no barriers in the K-loop.
// Per K-step (16i x 32j = 512 pairs):
//   e-frag (MFMA B-op): lane computes 8 exps in fp32, packs to bf16
//   y-frags (MFMA A-op): 2 coalesced dwordx4 from prebaked hi/lo planes
//   3 MFMAs: acc += Yhi@E + Ylo@E;  acc2 += Ones@E (denominator)
// D layout (verified m74/m89): col=lane&15 = i, row=quad*4+reg = cls.
// ---------------------------------------------------------------------------
__global__ __launch_bounds__(256) void simmain_kernel(
    const float* __restrict__ kq, const short* __restrict__ yfh,
    const short* __restrict__ yfl, float* __restrict__ numer,
    float* __restrict__ denom)
{
    __shared__ float ks[JC * 2];   // 2048 float2 = 16 KB, fp32 k-chunk

    const int tid  = threadIdx.x;
    const int wave = tid >> 6;
    const int lane = tid & 63;
    const int j0   = blockIdx.y * JC;

    {   // stage k chunk: 4096 floats, 4 x float4 per thread, coalesced
        const float4* src = (const float4*)(kq + 2 * j0);
        float4* dst = (float4*)ks;
#pragma unroll
        for (int p = 0; p < (JC * 2 / 4) / 256; ++p)
            dst[tid + 256 * p] = src[tid + 256 * p];
    }
    __syncthreads();

    const int i0   = (blockIdx.x * 4 + wave) * 16;
    const int m    = lane & 15;
    const int quad = lane >> 4;

    // q for this lane's test point, pre-scaled by log2(e) so e = exp2(logit')
    const float2 qv = *(const float2*)(kq + 2 * (NTR + i0 + m));
    const float q0 = qv.x * 1.4426950408889634f;
    const float q1 = qv.y * 1.4426950408889634f;

    f32x4 acc  = {0.f, 0.f, 0.f, 0.f};
    f32x4 acc2 = {0.f, 0.f, 0.f, 0.f};
    short8 ones;
#pragma unroll
    for (int t = 0; t < 8; ++t) ones[t] = (short)0x3F80;   // bf16 1.0

    const short8* __restrict__ yhp = ((const short8*)yfh) + (size_t)blockIdx.y * (STEPS * 64) + lane;
    const short8* __restrict__ ylp = ((const short8*)yfl) + (size_t)blockIdx.y * (STEPS * 64) + lane;
    const float4* __restrict__ kx  = ((const float4*)ks) + quad * 4;   // quad's j-octet

#pragma unroll 4
    for (int s = 0; s < STEPS; ++s) {
        const short8 yh = yhp[s * 64];          // coalesced dwordx4, L2-hot
        const short8 yl = ylp[s * 64];
        const float4* kp = kx + s * 16;         // quad-broadcast b128 reads
        const float4 ka = kp[0], kb = kp[1], kc = kp[2], kd = kp[3];

        const float e0 = exp2f(fmaf(q1, ka.y, q0 * ka.x));
        const float e1 = exp2f(fmaf(q1, ka.w, q0 * ka.z));
        const float e2 = exp2f(fmaf(q1, kb.y, q0 * kb.x));
        const float e3 = exp2f(fmaf(q1, kb.w, q0 * kb.z));
        const float e4 = exp2f(fmaf(q1, kc.y, q0 * kc.x));
        const float e5 = exp2f(fmaf(q1, kc.w, q0 * kc.z));
        const float e6 = exp2f(fmaf(q1, kd.y, q0 * kd.x));
        const float e7 = exp2f(fmaf(q1, kd.w, q0 * kd.z));

        short8 eb;
        eb[0] = f2bf(e0); eb[1] = f2bf(e1); eb[2] = f2bf(e2); eb[3] = f2bf(e3);
        eb[4] = f2bf(e4); eb[5] = f2bf(e5); eb[6] = f2bf(e6); eb[7] = f2bf(e7);

        acc  = __builtin_amdgcn_mfma_f32_16x16x32_bf16(yh,   eb, acc,  0, 0, 0);
        acc  = __builtin_amdgcn_mfma_f32_16x16x32_bf16(yl,   eb, acc,  0, 0, 0);
        acc2 = __builtin_amdgcn_mfma_f32_16x16x32_bf16(ones, eb, acc2, 0, 0, 0);
    }

    // Flush: lane holds numer[i0+m][quad*4+r] = acc[r]; dsum(i0+m) = acc2[*]
    float* nrow = numer + (size_t)(i0 + m) * NCLS + quad * 4;
#pragma unroll
    for (int r = 0; r < 4; ++r)
        atomicAdd(nrow + r, acc[r]);
    if (quad == 0)
        atomicAdd(denom + i0 + m, acc2[0]);
}

// ---------------------------------------------------------------------------
// Kernel 3: finalize — divide numerators by softmax denominator.
// ---------------------------------------------------------------------------
__global__ __launch_bounds__(256) void finalize_kernel(
    const float* __restrict__ numer, const float* __restrict__ denom,
    float* __restrict__ out)
{
    const int idx = blockIdx.x * 256 + threadIdx.x;   // < NT*NCLS
    out[idx] = numer[idx] / denom[idx >> 4];
}

// ---------------------------------------------------------------------------
extern "C" void kernel_launch(void* const* d_in, const int* in_sizes, int n_in,
                              void* d_out, int out_size, void* d_ws, size_t ws_size,
                              hipStream_t stream)
{
    const float* xtr = (const float*)d_in[0];   // [16384][512]
    const float* ytr = (const float*)d_in[1];   // [16384][16]
    const float* xt  = (const float*)d_in[2];   // [8192][512]
    const float* A   = (const float*)d_in[3];   // [512][2]
    float* out = (float*)d_out;                 // [8192][16]

    float* kq    = (float*)d_ws;                       // 49152 floats
    float* numer = kq + WS_KQ_F;                       // 131072 floats
    float* denom = numer + WS_NUMER_F;                 // 8192 floats
    short* yfh   = (short*)(denom + WS_DENOM_F);       // 262144 shorts (512 KB)
    short* yfl   = yfh + NSTEPS * 64 * 8;              // 262144 shorts (512 KB)

    // ws is poisoned 0xAA before every call: zero the accumulators.
    hipMemsetAsync(numer, 0, (WS_NUMER_F + WS_DENOM_F) * sizeof(float), stream);

    prepy_kernel<<<(NSTEPS * 64) / 256, 256, 0, stream>>>(ytr, yfh, yfl);
    proj_kernel<<<NROWS / 4, 256, 0, stream>>>(xtr, xt, A, kq);
    simmain_kernel<<<dim3(NT / 64, JS), 256, 0, stream>>>(kq, yfh, yfl, numer, denom);
    finalize_kernel<<<(NT * NCLS) / 256, 256, 0, stream>>>(numer, denom, out);
}

// Round 5
// 135.787 us; speedup vs baseline: 3.5429x; 1.0580x over previous
//
#include <hip/hip_runtime.h>
#include <hip/hip_bf16.h>
#include <math.h>

// Problem constants
#define DIM   512
#define NTR   16384
#define NT    8192
#define NCLS  16
#define NROWS (NTR + NT)   // 24576 projection rows

// simmain tiling: wave owns a 16-i tile; block = 4 waves = 64 i's, one j-chunk.
#define JS     16                  // j-splits (2048 blocks -> 8 blocks/CU)
#define JC     (NTR / JS)          // 1024 j per chunk
#define STEPS  (JC / 32)           // 32 K-steps (32 j each) per wave
#define NSTEPS (NTR / 32)          // 512 global K-steps

// ws layout (floats/shorts):
//   kq [24576][2] f32 | numer [8192][16] f32 | denom [8192] f32
//   yfh: 512 steps x 64 lanes x 8 bf16 (A-frag order, hi) | yfl: lo residual
#define WS_KQ_F    (NROWS * 2)           // 49152 floats
#define WS_NUMER_F (NT * NCLS)           // 131072 floats
#define WS_DENOM_F (NT)                  // 8192 floats
#define WS_ZERO_V4 ((WS_NUMER_F + WS_DENOM_F) / 4)   // 34816 float4s to zero

typedef __attribute__((ext_vector_type(8))) short short8;
typedef __attribute__((ext_vector_type(4))) float f32x4;
typedef __attribute__((ext_vector_type(4))) unsigned int uint4v;

static __device__ __forceinline__ short f2bf(float f) {   // RNE (prep only)
    unsigned u = __float_as_uint(f);
    return (short)((u + 0x7FFFu + ((u >> 16) & 1u)) >> 16);
}
static __device__ __forceinline__ float bf2f(short h) {
    return __uint_as_float(((unsigned)(unsigned short)h) << 16);
}
// Pack 2 positive floats to bf16x2 (round-half-up): 2 adds + 1 v_perm.
static __device__ __forceinline__ unsigned pkbf(float a, float b) {
    unsigned ua = __float_as_uint(a) + 0x8000u;
    unsigned ub = __float_as_uint(b) + 0x8000u;
    return __builtin_amdgcn_perm(ub, ua, 0x07060302);   // (bf(b)<<16)|bf(a)
}

// ---------------------------------------------------------------------------
// Kernel 1: fused projection. One wave per TWO rows (512-dim dot with A's 2
// cols), interleaved for ILP: 4 independent row-loads in flight per lane.
// ---------------------------------------------------------------------------
__global__ __launch_bounds__(256) void proj_kernel(
    const float* __restrict__ xtr, const float* __restrict__ xt,
    const float* __restrict__ A, float* __restrict__ kq)
{
    const int wave = threadIdx.x >> 6;
    const int lane = threadIdx.x & 63;
    const int row0 = blockIdx.x * 8 + wave * 2;

    const float* x0 = (row0 < NTR) ? (xtr + (size_t)row0 * DIM)
                                   : (xt + (size_t)(row0 - NTR) * DIM);
    const float* x1 = (row0 + 1 < NTR) ? (xtr + (size_t)(row0 + 1) * DIM)
                                       : (xt + (size_t)(row0 + 1 - NTR) * DIM);
    float a00 = 0.f, a01 = 0.f, a10 = 0.f, a11 = 0.f;
#pragma unroll
    for (int t = 0; t < 2; ++t) {
        const int d = lane * 4 + t * 256;
        float4 u = *(const float4*)(x0 + d);
        float4 v = *(const float4*)(x1 + d);
        float4 A0 = *(const float4*)(A + 2 * d);
        float4 A1 = *(const float4*)(A + 2 * d + 4);
        a00 += u.x * A0.x + u.y * A0.z + u.z * A1.x + u.w * A1.z;
        a01 += u.x * A0.y + u.y * A0.w + u.z * A1.y + u.w * A1.w;
        a10 += v.x * A0.x + v.y * A0.z + v.z * A1.x + v.w * A1.z;
        a11 += v.x * A0.y + v.y * A0.w + v.z * A1.y + v.w * A1.w;
    }
#pragma unroll
    for (int off = 32; off >= 1; off >>= 1) {
        a00 += __shfl_xor(a00, off, 64);
        a01 += __shfl_xor(a01, off, 64);
        a10 += __shfl_xor(a10, off, 64);
        a11 += __shfl_xor(a11, off, 64);
    }
    if (lane == 0)
        *(float4*)(kq + row0 * 2) = make_float4(a00, a01, a10, a11);
}

// ---------------------------------------------------------------------------
// Kernel 1b: bake ytr^T into bf16 hi/lo planes in EXACT MFMA A-fragment order,
// and zero the numer/denom accumulators (absorbs the former memset node).
// ---------------------------------------------------------------------------
__global__ __launch_bounds__(256) void prepy_kernel(
    const float* __restrict__ ytr, short* __restrict__ yfh,
    short* __restrict__ yfl, float* __restrict__ zbase)
{
    const int idx  = blockIdx.x * 256 + threadIdx.x;  // 0 .. NSTEPS*64-1 (32768)
    // zero numer+denom (34816 float4s over 32768 threads)
    float4 z = make_float4(0.f, 0.f, 0.f, 0.f);
    for (int p = idx; p < WS_ZERO_V4; p += NSTEPS * 64)
        ((float4*)zbase)[p] = z;

    const int l    = idx & 63;
    const int s    = idx >> 6;
    const int cls  = l & 15;
    const int jb   = s * 32 + (l >> 4) * 8;
    short8 hi, lo;
#pragma unroll
    for (int t = 0; t < 8; ++t) {
        float v = ytr[(size_t)(jb + t) * NCLS + cls];
        short h = f2bf(v);
        hi[t] = h;
        lo[t] = f2bf(v - bf2f(h));
    }
    ((short8*)yfh)[idx] = hi;
    ((short8*)yfl)[idx] = lo;
}

// ---------------------------------------------------------------------------
// Kernel 2: main. Grid (NT/64, JS) = (128, 16) = 2048 blocks (8 blocks/CU,
// 32 waves/CU). Wave owns a 16-i tile; block stages its 1024-j k-chunk
// (fp32, 8 KB) in LDS once; no barriers in the K-loop.
// Per K-step (16i x 32j): 8 fp32 exps -> v_perm bf16 pack (12 insts) ->
// 3 MFMAs (Yhi@E + Ylo@E -> numer, Ones@E -> denom).
// D layout (verified m74/m89): col=lane&15 = i, row=quad*4+reg = cls.
// ---------------------------------------------------------------------------
__global__ __launch_bounds__(256) void simmain_kernel(
    const float* __restrict__ kq, const short* __restrict__ yfh,
    const short* __restrict__ yfl, float* __restrict__ numer,
    float* __restrict__ denom)
{
    __shared__ float ks[JC * 2];   // 1024 float2 = 8 KB, fp32 k-chunk

    const int tid  = threadIdx.x;
    const int wave = tid >> 6;
    const int lane = tid & 63;
    const int j0   = blockIdx.y * JC;

    {   // stage k chunk: 2048 floats, 2 x float4 per thread, coalesced
        const float4* src = (const float4*)(kq + 2 * j0);
        float4* dst = (float4*)ks;
#pragma unroll
        for (int p = 0; p < (JC * 2 / 4) / 256; ++p)
            dst[tid + 256 * p] = src[tid + 256 * p];
    }
    __syncthreads();

    const int i0   = (blockIdx.x * 4 + wave) * 16;
    const int m    = lane & 15;
    const int quad = lane >> 4;

    // q for this lane's test point, pre-scaled by log2(e) so e = exp2(logit')
    const float2 qv = *(const float2*)(kq + 2 * (NTR + i0 + m));
    const float q0 = qv.x * 1.4426950408889634f;
    const float q1 = qv.y * 1.4426950408889634f;

    f32x4 acc  = {0.f, 0.f, 0.f, 0.f};
    f32x4 acc2 = {0.f, 0.f, 0.f, 0.f};
    short8 ones;
#pragma unroll
    for (int t = 0; t < 8; ++t) ones[t] = (short)0x3F80;   // bf16 1.0

    const short8* __restrict__ yhp = ((const short8*)yfh) + (size_t)blockIdx.y * (STEPS * 64) + lane;
    const short8* __restrict__ ylp = ((const short8*)yfl) + (size_t)blockIdx.y * (STEPS * 64) + lane;
    const float4* __restrict__ kx  = ((const float4*)ks) + quad * 4;   // quad's j-octet

#pragma unroll 4
    for (int s = 0; s < STEPS; ++s) {
        const short8 yh = yhp[s * 64];          // coalesced dwordx4, L2-hot
        const short8 yl = ylp[s * 64];
        const float4* kp = kx + s * 16;         // quad-broadcast b128 reads
        const float4 ka = kp[0], kb = kp[1], kc = kp[2], kd = kp[3];

        const float e0 = exp2f(fmaf(q1, ka.y, q0 * ka.x));
        const float e1 = exp2f(fmaf(q1, ka.w, q0 * ka.z));
        const float e2 = exp2f(fmaf(q1, kb.y, q0 * kb.x));
        const float e3 = exp2f(fmaf(q1, kb.w, q0 * kb.z));
        const float e4 = exp2f(fmaf(q1, kc.y, q0 * kc.x));
        const float e5 = exp2f(fmaf(q1, kc.w, q0 * kc.z));
        const float e6 = exp2f(fmaf(q1, kd.y, q0 * kd.x));
        const float e7 = exp2f(fmaf(q1, kd.w, q0 * kd.z));

        uint4v ep;
        ep[0] = pkbf(e0, e1); ep[1] = pkbf(e2, e3);
        ep[2] = pkbf(e4, e5); ep[3] = pkbf(e6, e7);
        const short8 eb = __builtin_bit_cast(short8, ep);

        acc  = __builtin_amdgcn_mfma_f32_16x16x32_bf16(yh,   eb, acc,  0, 0, 0);
        acc  = __builtin_amdgcn_mfma_f32_16x16x32_bf16(yl,   eb, acc,  0, 0, 0);
        acc2 = __builtin_amdgcn_mfma_f32_16x16x32_bf16(ones, eb, acc2, 0, 0, 0);
    }

    // Flush: lane holds numer[i0+m][quad*4+r] = acc[r]; dsum(i0+m) = acc2[*]
    float* nrow = numer + (size_t)(i0 + m) * NCLS + quad * 4;
#pragma unroll
    for (int r = 0; r < 4; ++r)
        atomicAdd(nrow + r, acc[r]);
    if (quad == 0)
        atomicAdd(denom + i0 + m, acc2[0]);
}

// ---------------------------------------------------------------------------
// Kernel 3: finalize — divide numerators by softmax denominator.
// ---------------------------------------------------------------------------
__global__ __launch_bounds__(256) void finalize_kernel(
    const float* __restrict__ numer, const float* __restrict__ denom,
    float* __restrict__ out)
{
    const int idx = blockIdx.x * 256 + threadIdx.x;   // < NT*NCLS
    out[idx] = numer[idx] / denom[idx >> 4];
}

// ---------------------------------------------------------------------------
extern "C" void kernel_launch(void* const* d_in, const int* in_sizes, int n_in,
                              void* d_out, int out_size, void* d_ws, size_t ws_size,
                              hipStream_t stream)
{
    const float* xtr = (const float*)d_in[0];   // [16384][512]
    const float* ytr = (const float*)d_in[1];   // [16384][16]
    const float* xt  = (const float*)d_in[2];   // [8192][512]
    const float* A   = (const float*)d_in[3];   // [512][2]
    float* out = (float*)d_out;                 // [8192][16]

    float* kq    = (float*)d_ws;                       // 49152 floats
    float* numer = kq + WS_KQ_F;                       // 131072 floats
    float* denom = numer + WS_NUMER_F;                 // 8192 floats
    short* yfh   = (short*)(denom + WS_DENOM_F);       // 262144 shorts (512 KB)
    short* yfl   = yfh + NSTEPS * 64 * 8;              // 262144 shorts (512 KB)

    prepy_kernel<<<(NSTEPS * 64) / 256, 256, 0, stream>>>(ytr, yfh, yfl, numer);
    proj_kernel<<<NROWS / 8, 256, 0, stream>>>(xtr, xt, A, kq);
    simmain_kernel<<<dim3(NT / 64, JS), 256, 0, stream>>>(kq, yfh, yfl, numer, denom);
    finalize_kernel<<<(NT * NCLS) / 256, 256, 0, stream>>>(numer, denom, out);
}